// Round 7
// baseline (477.283 us; speedup 1.0000x reference)
//
#include <hip/hip_runtime.h>
#include <math.h>

typedef _Float16 half8 __attribute__((ext_vector_type(8)));
typedef float floatx4 __attribute__((ext_vector_type(4)));

namespace {
constexpr int Kc = 1024;   // num_embeddings
constexpr int Dd = 64;     // embedding_dim
constexpr float MARGIN = 4e-4f;   // >= 2*B'; B' ~ 6.5e-5 (fp16 quant + numpy fl() @ |dist|~64)

// numpy pairwise_sum of squares, n=64 (8 accumulators + fixed combine tree),
// squares rounded before summing (contract off). contiguous input.
__device__ inline float np_sumsq64(const float* __restrict__ a) {
#pragma clang fp contract(off)
    float r[8];
    #pragma unroll
    for (int j = 0; j < 8; ++j) r[j] = a[j] * a[j];
    #pragma unroll
    for (int i = 8; i < 64; i += 8) {
        #pragma unroll
        for (int j = 0; j < 8; ++j) {
            float s = a[i + j] * a[i + j];
            r[j] = r[j] + s;
        }
    }
    return ((r[0] + r[1]) + (r[2] + r[3])) + ((r[4] + r[5]) + (r[6] + r[7]));
}

// exact numpy fp32 dist: fl( fl(xx+ee_k) - 2*g ), g = sequential FMA d=0..63
// x contiguous (LDS), e from global emb row (float4 loads, sequential FMA order kept)
__device__ inline float np_dist(const float* __restrict__ x,
                                const float* __restrict__ emb, int k,
                                float xx, float eek) {
    const float4* e4 = (const float4*)(emb + (size_t)k * Dd);
    float g = 0.f;
    #pragma unroll
    for (int i = 0; i < 16; ++i) {
        float4 v = e4[i];
        g = fmaf(x[i * 4 + 0], v.x, g);
        g = fmaf(x[i * 4 + 1], v.y, g);
        g = fmaf(x[i * 4 + 2], v.z, g);
        g = fmaf(x[i * 4 + 3], v.w, g);
    }
    float A = xx + eek;
    return fmaf(-2.f, g, A);
}

// ---- prep: ee[k] = numpy-order ||e_k||^2 ; emb16 = fp16 codebook ----
__global__ void k_prep(const float* __restrict__ emb, float* __restrict__ ee,
                       _Float16* __restrict__ emb16) {
    int k = blockIdx.x * blockDim.x + threadIdx.x;
    const float* e = emb + (size_t)k * Dd;
    ee[k] = np_sumsq64(e);
    #pragma unroll
    for (int d = 0; d < Dd; ++d) emb16[k * Dd + d] = (_Float16)e[d];
}

// ---- main: 1024 blocks x 256 thr; 64 pixels/block ----
// Phase 1 (barriers, LDS-only): MFMA screen over 8 codebook chunks.
// Phase 2: merge + exact rescore (x from LDS).
// Phase 3 (post-barrier, store burst): quant + enc zero-fill fused w/ one-hot.
__global__ __launch_bounds__(256) void k_main(
    const float* __restrict__ inputs, const float* __restrict__ emb,
    const float* __restrict__ ee_g, const _Float16* __restrict__ emb16,
    float* __restrict__ quant, float* __restrict__ enc, float* __restrict__ idx_out,
    unsigned int* __restrict__ hist, float* __restrict__ partials)
{
    __shared__ short  smemB[128 * 72];   // 128 codes/chunk, stride 72 halfs
    __shared__ float  eeS[Kc];
    __shared__ float  xS[64][65];        // exact fp32 x per pixel (stride 65: 2-way free)
    __shared__ float  cDT[16][65], cD2T[16][65];   // [lane][pixel], padded
    __shared__ int    cIT[16][65];
    __shared__ float  red[64];
    __shared__ int    bidxS[64];
    __shared__ int    flagged[64];
    __shared__ int    nflag;
    __shared__ float  fbD[256];
    __shared__ int    fbI[256];

    const int tid = threadIdx.x;
    const int w   = tid >> 6;     // wave 0..3
    const int ln  = tid & 63;
    const int lm  = ln & 15;      // MFMA A-row lane (pixel) / B col lane (code)
    const int lq  = ln >> 4;      // quad 0..3

    if (tid == 0) nflag = 0;
    #pragma unroll
    for (int i = 0; i < 4; ++i) eeS[tid + i * 256] = ee_g[tid + i * 256];

    // A fragments: lane -> pixel (w*16+lm), d = lq*8+j (+32 for a1).
    // Also stash exact fp32 x into LDS (each (d,pixel) covered exactly once).
    const int pA = w * 16 + lm;
    const int nA = blockIdx.x * 64 + pA;
    const float* xA = inputs + (size_t)(nA >> 10) * (Dd * 1024) + (nA & 1023);
    half8 a0, a1;
    #pragma unroll
    for (int j = 0; j < 8; ++j) {
        float v0 = xA[(lq * 8 + j) * 1024];
        float v1 = xA[(lq * 8 + j + 32) * 1024];
        a0[j] = (_Float16)v0;
        a1[j] = (_Float16)v1;
        xS[pA][lq * 8 + j]      = v0;
        xS[pA][lq * 8 + j + 32] = v1;
    }

    float b1[4], b2[4];
    int   i1[4];
    #pragma unroll
    for (int r = 0; r < 4; ++r) { b1[r] = INFINITY; b2[r] = INFINITY; i1[r] = 0; }

    for (int c = 0; c < 8; ++c) {            // 8 chunks x 128 codes — LDS-only region
        __syncthreads();                     // prev chunk reads done (+xS/eeS on c=0)
        #pragma unroll
        for (int u = 0; u < 4; ++u) {        // stage 16KB: 4 x 16B per thread
            int unit = u * 256 + tid;
            int row = unit >> 3, c8 = unit & 7;
            half8 v = *(const half8*)(emb16 + ((size_t)(c * 128 + row) * 64) + c8 * 8);
            *(half8*)(smemB + row * 72 + c8 * 8) = v;
        }
        __syncthreads();

        #pragma unroll
        for (int tt = 0; tt < 8; ++tt) {
            const int r = tt * 16 + lm;
            const int kn = c * 128 + r;          // ascending code id
            const half8 bb0 = *(const half8*)(smemB + r * 72 + lq * 8);
            const half8 bb1 = *(const half8*)(smemB + r * 72 + 32 + lq * 8);
            floatx4 acc = {0.f, 0.f, 0.f, 0.f};
            acc = __builtin_amdgcn_mfma_f32_16x16x32_f16(a0, bb0, acc, 0, 0, 0);
            acc = __builtin_amdgcn_mfma_f32_16x16x32_f16(a1, bb1, acc, 0, 0, 0);
            const float eev = eeS[kn];
            #pragma unroll
            for (int r4 = 0; r4 < 4; ++r4) {     // acc[r4] -> pixel w*16 + lq*4 + r4
                float s = fmaf(-2.f, acc[r4], eev);
                bool lt1 = s < b1[r4], lt2 = s < b2[r4];
                b2[r4] = lt1 ? b1[r4] : (lt2 ? s : b2[r4]);
                b1[r4] = lt1 ? s : b1[r4];
                i1[r4] = lt1 ? kn : i1[r4];
            }
        }
    }
    __syncthreads();

    #pragma unroll
    for (int r = 0; r < 4; ++r) {
        int p = w * 16 + lq * 4 + r;
        cDT[lm][p] = b1[r]; cIT[lm][p] = i1[r]; cD2T[lm][p] = b2[r];
    }
    __syncthreads();

    if (tid < 64) {    // one merge thread per pixel; stride-1 conflict-free reads
        const int p = tid;
        const int n = blockIdx.x * 64 + p;
        float amin = INFINITY;
        #pragma unroll
        for (int cc = 0; cc < 16; ++cc) amin = fminf(amin, cDT[cc][p]);
        const float M = amin + MARGIN;
        bool flag = false;
        #pragma unroll
        for (int cc = 0; cc < 16; ++cc) flag |= (cD2T[cc][p] <= M);  // 3rd may hide
        if (flag) {
            int s = atomicAdd(&nflag, 1);
            flagged[s] = p;
        } else {
            const float xx = np_sumsq64(&xS[p][0]);
            float bd = INFINITY; int bi = 0x7fffffff;
            for (int cc = 0; cc < 16; ++cc)
                if (cDT[cc][p] <= M) {
                    int k = cIT[cc][p];
                    float d = np_dist(&xS[p][0], emb, k, xx, eeS[k]);
                    if (d < bd || (d == bd && k < bi)) { bd = d; bi = k; }
                }
            bidxS[p] = bi;
            red[p] = bd;
            idx_out[n] = (float)bi;
            atomicAdd(hist + bi, 1u);
        }
    }
    __syncthreads();

    const int nf = nflag;   // uniform
    for (int f = 0; f < nf; ++f) {   // rare: exact full scan for ambiguous pixels
        const int p = flagged[f];
        const float* xp = &xS[p][0];           // LDS broadcast reads
        const float xx = np_sumsq64(xp);
        float bd = INFINITY; int bi = 0;
        #pragma unroll
        for (int q = 0; q < 4; ++q) {          // ascending k, strict <
            int k = tid * 4 + q;
            float d = np_dist(xp, emb, k, xx, eeS[k]);
            bool lt = d < bd;
            bd = lt ? d : bd; bi = lt ? k : bi;
        }
        fbD[tid] = bd; fbI[tid] = bi;
        __syncthreads();
        if (tid == 0) {
            float gd = INFINITY; int gi = 0;
            for (int t2 = 0; t2 < 256; ++t2)   // ascending tid = ascending k
                if (fbD[t2] < gd) { gd = fbD[t2]; gi = fbI[t2]; }
            bidxS[p] = gi;
            red[p] = gd;
            idx_out[blockIdx.x * 64 + p] = (float)gi;
            atomicAdd(hist + gi, 1u);
        }
        __syncthreads();
    }
    // ---- last barrier of the kernel: everything below is an unthrottled store burst

    if (tid < 64) {   // loss partial over the block's 64 pixels
        float v = red[tid];
        #pragma unroll
        for (int off = 32; off > 0; off >>= 1) v += __shfl_down(v, off, 64);
        if (ln == 0) partials[blockIdx.x] = v;
    }

    // quant: lane=pixel (coalesced stores per d), wave w covers d = w*16..w*16+15
    {
        const int n = blockIdx.x * 64 + ln;
        const int bi = bidxS[ln];
        float* qout = quant + (size_t)(n >> 10) * (Dd * 1024) + (n & 1023);
        const float4* eb = (const float4*)(emb + (size_t)bi * Dd);
        #pragma unroll
        for (int i = 0; i < 4; ++i) {
            float4 v = eb[w * 4 + i];
            const int d0 = w * 16 + i * 4;
            qout[(d0 + 0) * 1024] = v.x;
            qout[(d0 + 1) * 1024] = v.y;
            qout[(d0 + 2) * 1024] = v.z;
            qout[(d0 + 3) * 1024] = v.w;
        }
    }

    // enc: zero-fill fused with one-hot patch. Thread (p=tid>>2, q=tid&3) owns
    // pixel p's float4 indices f = i*4+q (i=0..63); 4 lanes cover a 64B line.
    {
        const int p = tid >> 2, q = tid & 3;
        const int bi = bidxS[p];
        const int ft = bi >> 2;                 // target float4 index in row
        const int it = ft >> 2, qt = ft & 3, et = bi & 3;
        floatx4* erow = (floatx4*)enc + ((size_t)(blockIdx.x * 64 + p)) * 256;
        #pragma unroll 8
        for (int i = 0; i < 64; ++i) {
            floatx4 v = {0.f, 0.f, 0.f, 0.f};
            if (q == qt && i == it) v[et] = 1.0f;
            __builtin_nontemporal_store(v, &erow[i * 4 + q]);
        }
    }
}

// ---- final: perplexity from histogram, loss from partials ----
__global__ __launch_bounds__(1024) void k_fin(
    const unsigned int* __restrict__ hist, const float* __restrict__ partials,
    float* __restrict__ loss_out, float* __restrict__ perp_out)
{
    __shared__ double sd[1024];
    int tid = threadIdx.x;
    double p = (double)hist[tid] * (1.0 / 65536.0);
    sd[tid] = p * log(p + 1e-10);
    __syncthreads();
    for (int s = 512; s > 0; s >>= 1) {
        if (tid < s) sd[tid] += sd[tid + s];
        __syncthreads();
    }
    double ent = sd[0];
    __syncthreads();
    sd[tid] = (double)partials[tid];
    __syncthreads();
    for (int s = 512; s > 0; s >>= 1) {
        if (tid < s) sd[tid] += sd[tid + s];
        __syncthreads();
    }
    if (tid == 0) {
        double perp = exp(-ent);
        double mean = sd[0] * (1.0 / 4194304.0);
        double loss = 1.25 * mean + 0.1 * (1024.0 - perp) / 1024.0;
        loss_out[0] = (float)loss;
        perp_out[0] = (float)perp;
    }
}
} // namespace

extern "C" void kernel_launch(void* const* d_in, const int* in_sizes, int n_in,
                              void* d_out, int out_size, void* d_ws, size_t ws_size,
                              hipStream_t stream)
{
    const float* inputs = (const float*)d_in[0];   // [64,64,32,32] fp32
    const float* emb    = (const float*)d_in[1];   // [1024,64] fp32
    float* out = (float*)d_out;

    float* loss_out = out;                            // [1]
    float* quant    = out + 1;                        // [64,64,32,32]
    float* perp_out = out + 1 + 4194304;              // [1]
    float* enc      = out + 2 + 4194304;              // [65536,1024]
    float* idx_out  = out + 2 + 4194304 + 67108864;   // [65536,1]

    unsigned int* hist = (unsigned int*)d_ws;         // [1024] u32
    float* partials    = (float*)d_ws + 1024;         // [1024] f32
    float* ee          = (float*)d_ws + 2048;         // [1024] f32
    _Float16* emb16    = (_Float16*)((float*)d_ws + 3072);  // [1024*64] f16

    (void)hipMemsetAsync(d_ws, 0, 2048 * sizeof(float), stream);  // hist + partials
    k_prep<<<Kc / 256, 256, 0, stream>>>(emb, ee, emb16);
    k_main<<<65536 / 64, 256, 0, stream>>>(inputs, emb, ee, emb16,
                                           quant, enc, idx_out, hist, partials);
    k_fin<<<1, 1024, 0, stream>>>(hist, partials, loss_out, perp_out);
}